// Round 8
// baseline (310.645 us; speedup 1.0000x reference)
//
#include <hip/hip_runtime.h>
#include <hip/hip_bf16.h>

#define R_TOT  1048576      // B*N*K = 16*2048*32 rows
#define NPT    2048         // points per batch
#define NCHUNK 4096         // R_TOT / 256

using bf16x8 = __attribute__((ext_vector_type(8))) short;
using f32x4  = __attribute__((ext_vector_type(4))) float;

#define MFMA(A,B,C) __builtin_amdgcn_mfma_f32_16x16x32_bf16((A),(B),(C),0,0,0)

__device__ __forceinline__ unsigned short f2bf(float f){
  unsigned u = __builtin_bit_cast(unsigned, f);
  return (unsigned short)((u + 0x7fffu + ((u >> 16) & 1u)) >> 16);
}
__device__ __forceinline__ unsigned pk2(float lo, float hi){
  return (unsigned)f2bf(lo) | ((unsigned)f2bf(hi) << 16);
}
// order-preserving float->uint (handles negative d2 from fp cancellation)
__device__ __forceinline__ unsigned fu(float f){
  unsigned u = __builtin_bit_cast(unsigned, f);
  return u ^ (0x80000000u | (unsigned)((int)u >> 31));
}

// ---------------- Kernel A: exact 32-NN, full-LDS bst + accept-mask recovery ------
__global__ __launch_bounds__(256) void kA(const float* __restrict__ a,
                                          const float* __restrict__ b,
                                          float* __restrict__ xd,     // [3][R_TOT]
                                          float* __restrict__ part1)  // [2048][28]
{
  __shared__ float4 bst[NPT];        // ALL candidates {x,y,z,|b|^2} (32 KB)
  __shared__ int    win[16][33];
  __shared__ int    eqb[16][16];
  __shared__ int    cLT[16], cEQ[16];
  __shared__ float  wstats[4][27];
  const int tid = threadIdx.x;
  const int bb    = blockIdx.x >> 7;           // 128 blocks per batch
  const int qbase = (blockIdx.x & 127) << 4;   // 16 queries per block
  const float* __restrict__ ap = a + bb*3*NPT;
  const float* __restrict__ bp = b + bb*3*NPT;

  const int sub = tid & 15;       // lane within query group
  const int qb  = tid >> 4;       // query within block (0..15)
  const int n   = qbase + qb;
  const float ax = ap[n], ay = ap[NPT+n], az = ap[2*NPT+n];
  const float a2 = (ax*ax + ay*ay) + az*az;

  // load full candidate set + pre-zero recovery buffers
  for (int i = tid; i < NPT; i += 256){
    const float X = bp[i], Y = bp[NPT+i], Z = bp[2*NPT+i];
    bst[i] = make_float4(X, Y, Z, (X*X + Y*Y) + Z*Z);
  }
  for (int i = tid; i < 16*33; i += 256) (&win[0][0])[i] = 0;
  for (int i = tid; i < 16*16; i += 256) (&eqb[0][0])[i] = 0;
  if (tid < 16){ cLT[tid] = 0; cEQ[tid] = 0; }
  __syncthreads();

  float s[14];
  #pragma unroll
  for (int j = 0; j < 14; ++j) s[j] = 3.0e38f;
  float bd[6]; int cnt = 0;
  float tau;
  unsigned long long m0 = 0ull, m1 = 0ull;    // accept mask, 128 candidates/lane

  auto dist = [&](int li)->float{
    const float4 bc = bst[li];
    const float dot = fmaf(az, bc.z, fmaf(ay, bc.y, ax*bc.x));
    return fmaf(-2.f, dot, a2 + bc.w);
  };
  auto insert = [&](float d){   // sorted ascending, drop current max
    #pragma unroll
    for (int j = 13; j >= 1; --j){
      const bool cj  = d < s[j];
      const bool cj1 = d < s[j-1];
      s[j] = cj ? (cj1 ? s[j-1] : d) : s[j];
    }
    s[0] = fminf(s[0], d);
  };
  auto flush = [&](){
    #pragma unroll
    for (int t = 0; t < 6; ++t){
      if (t < cnt && bd[t] < s[13]) insert(bd[t]);
    }
    cnt = 0;
  };

  // ---- tau seed (max of first 64 group candidates >= running 32nd) ----
  {
    float m = dist(sub);
    m = fmaxf(m, dist(sub + 16));
    m = fmaxf(m, dist(sub + 32));
    m = fmaxf(m, dist(sub + 48));
    m = fmaxf(m, __shfl_xor(m, 1));
    m = fmaxf(m, __shfl_xor(m, 2));
    m = fmaxf(m, __shfl_xor(m, 4));
    m = fmaxf(m, __shfl_xor(m, 8));
    tau = m;
  }

  // ---- filtered single-pass scan over all 128 candidates/lane ----
  for (int jj = 0; jj < 128; jj += 4){
    #pragma unroll
    for (int u = 0; u < 4; ++u){
      const int k = jj + u;
      const float d = dist(sub + (k << 4));
      if (d <= tau && d < s[13]){
        #pragma unroll
        for (int t2 = 0; t2 < 6; ++t2) if (cnt == t2) bd[t2] = d;
        ++cnt;
        if (k < 64) m0 |= 1ull << k; else m1 |= 1ull << (k - 64);
      }
    }
    if (__any(cnt > 2)) flush();
    if ((jj & 12) == 12){   // refresh tau every 16 candidates: group-max of s[1]
      float m = s[1];
      m = fmaxf(m, __shfl_xor(m, 1));
      m = fmaxf(m, __shfl_xor(m, 2));
      m = fmaxf(m, __shfl_xor(m, 4));
      m = fmaxf(m, __shfl_xor(m, 8));
      tau = fminf(tau, m);
    }
  }
  flush();

  // ---- exact 32nd value via bracketed uint bisection over retained values ----
  unsigned du[14];
  #pragma unroll
  for (int j = 0; j < 14; ++j) du[j] = fu(s[j]);
  unsigned lo, hi;
  {
    unsigned mn = du[0];
    mn = min(mn, (unsigned)__shfl_xor((int)mn, 1));
    mn = min(mn, (unsigned)__shfl_xor((int)mn, 2));
    mn = min(mn, (unsigned)__shfl_xor((int)mn, 4));
    mn = min(mn, (unsigned)__shfl_xor((int)mn, 8));
    unsigned mx1 = du[1];
    mx1 = max(mx1, (unsigned)__shfl_xor((int)mx1, 1));
    mx1 = max(mx1, (unsigned)__shfl_xor((int)mx1, 2));
    mx1 = max(mx1, (unsigned)__shfl_xor((int)mx1, 4));
    mx1 = max(mx1, (unsigned)__shfl_xor((int)mx1, 8));
    lo = mn; hi = mx1 + 1u;
  }
  while (__any(hi - lo > 1u)){
    const unsigned mid = lo + ((hi - lo) >> 1);
    int cl = 0;
    #pragma unroll
    for (int j = 0; j < 14; ++j) cl += (du[j] < mid) ? 1 : 0;
    cl += __shfl_xor(cl, 1); cl += __shfl_xor(cl, 2);
    cl += __shfl_xor(cl, 4); cl += __shfl_xor(cl, 8);
    if (cl >= 32) hi = mid; else lo = mid;
  }
  const unsigned ustar = lo;

  // ---- index recovery: iterate ONLY accepted candidates (bst still resident) ----
  #pragma unroll
  for (int w = 0; w < 2; ++w){
    unsigned long long m = w ? m1 : m0;
    while (m){
      const int k = __ffsll(m) - 1; m &= m - 1ull;
      const int li = sub + ((w*64 + k) << 4);
      const unsigned ud = fu(dist(li));
      if (ud < ustar){
        const int slot = atomicAdd(&cLT[qb], 1);
        if (slot < 32) win[qb][slot] = li;
      } else if (ud == ustar){
        const int slot = atomicAdd(&cEQ[qb], 1);
        if (slot < 16) eqb[qb][slot] = li;
      }
    }
  }
  __syncthreads();

  // ---- boundary fill (lowest-index equals, matches stable top_k) ----
  if (sub == 0){
    const int c1 = cLT[qb] < 32 ? cLT[qb] : 32;
    const int totEQ = cEQ[qb];
    const int need = 32 - c1;
    const int stored = totEQ < 16 ? totEQ : 16;
    if (totEQ == need){
      const int lim = need < stored ? need : stored;
      for (int e = 0; e < lim; ++e) win[qb][c1 + e] = eqb[qb][e];
      for (int e = lim; e < need; ++e) win[qb][c1 + e] = eqb[qb][0];
    } else {
      int last = -1;
      for (int r = 0; r < need; ++r){
        int mm = 0x7FFFFFFF;
        for (int e = 0; e < stored; ++e){
          const int v = eqb[qb][e];
          if (v > last && v < mm) mm = v;
        }
        if (mm == 0x7FFFFFFF) mm = eqb[qb][0];
        win[qb][c1 + r] = mm; last = mm;
      }
    }
  }
  __syncthreads();

  // ---- diffs (2 winners per lane) + distributive stats partials ----
  float sdx=0,sdy=0,sdz=0,gxx=0,gxy=0,gxz=0,gyy=0,gyz=0,gzz=0;
  const int rbase = (bb*NPT + n) * 32;
  float ox[2], oy[2], oz[2];
  #pragma unroll
  for (int r = 0; r < 2; ++r){
    const int w = win[qb][sub*2 + r];
    const float dx = ap[w] - ax, dy = ap[NPT+w] - ay, dz = ap[2*NPT+w] - az;
    ox[r]=dx; oy[r]=dy; oz[r]=dz;
    sdx += dx; sdy += dy; sdz += dz;
    gxx = fmaf(dx,dx,gxx); gxy = fmaf(dx,dy,gxy); gxz = fmaf(dx,dz,gxz);
    gyy = fmaf(dy,dy,gyy); gyz = fmaf(dy,dz,gyz); gzz = fmaf(dz,dz,gzz);
  }
  *(float2*)&xd[0*R_TOT + rbase + sub*2] = make_float2(ox[0],ox[1]);
  *(float2*)&xd[1*R_TOT + rbase + sub*2] = make_float2(oy[0],oy[1]);
  *(float2*)&xd[2*R_TOT + rbase + sub*2] = make_float2(oz[0],oz[1]);

  float S[27];
  S[0]=sdx; S[1]=sdy; S[2]=sdz; S[3]=2.f*ax; S[4]=2.f*ay; S[5]=2.f*az;
  S[6]=gxx; S[7]=gxy; S[8]=gxz; S[9]=sdx*ax; S[10]=sdx*ay; S[11]=sdx*az;
  S[12]=gyy; S[13]=gyz; S[14]=sdy*ax; S[15]=sdy*ay; S[16]=sdy*az;
  S[17]=gzz; S[18]=sdz*ax; S[19]=sdz*ay; S[20]=sdz*az;
  S[21]=2.f*ax*ax; S[22]=2.f*ax*ay; S[23]=2.f*ax*az;
  S[24]=2.f*ay*ay; S[25]=2.f*ay*az; S[26]=2.f*az*az;
  #pragma unroll
  for (int i = 0; i < 27; ++i){
    float v = S[i];
    v += __shfl_down(v,32); v += __shfl_down(v,16); v += __shfl_down(v,8);
    v += __shfl_down(v,4);  v += __shfl_down(v,2);  v += __shfl_down(v,1);
    if ((tid & 63) == 0) wstats[tid>>6][i] = v;
  }
  __syncthreads();
  if (tid < 27)
    part1[blockIdx.x*28 + tid] = (wstats[0][tid]+wstats[1][tid]) + (wstats[2][tid]+wstats[3][tid]);
}

// ---------------- Kernel B0: reduce part1 over 2048 blocks ------------------------
__global__ __launch_bounds__(256) void kB0(const float* __restrict__ part1,
                                           float* __restrict__ st)   // [27]
{
  __shared__ float red[256];
  const int i = blockIdx.x;  // 0..26
  float ssum = 0.f;
  for (int k = threadIdx.x; k < 2048; k += 256) ssum += part1[k*28 + i];
  red[threadIdx.x] = ssum;
  __syncthreads();
  for (int w = 128; w > 0; w >>= 1){
    if (threadIdx.x < w) red[threadIdx.x] += red[threadIdx.x + w];
    __syncthreads();
  }
  if (threadIdx.x == 0) st[i] = red[0];
}

// ---------------- Kernel B2: finalize BN1 scale/bias (analytic) -------------------
__global__ __launch_bounds__(64) void kB2(const float* __restrict__ st_in,
                                          const float* __restrict__ W1,
                                          const float* __restrict__ g1,
                                          const float* __restrict__ b1,
                                          float* __restrict__ sb1)
{
  __shared__ float st[27];
  const int tid = threadIdx.x;
  if (tid < 27) st[tid] = st_in[tid];
  __syncthreads();
  const int o = tid;
  const float invR = 1.f / (float)R_TOT;
  float mu[6], w[6];
  #pragma unroll
  for (int c = 0; c < 6; ++c){ mu[c] = st[c]*invR; w[c] = W1[o*6+c]; }
  float mean = 0.f;
  #pragma unroll
  for (int c = 0; c < 6; ++c) mean = fmaf(w[c], mu[c], mean);
  float var = 0.f;
  #pragma unroll
  for (int c = 0; c < 6; ++c)
    #pragma unroll
    for (int c2 = 0; c2 < 6; ++c2){
      const int lo = c < c2 ? c : c2, hi = c < c2 ? c2 : c;
      const int ti = 6*lo - lo*(lo-1)/2 + (hi - lo);
      float cov = st[6+ti]*invR - mu[c]*mu[c2];
      var = fmaf(w[c]*w[c2], cov, var);
    }
  float sc = g1[o] / sqrtf(var + 1e-5f);
  sb1[o] = sc; sb1[64+o] = b1[o] - mean*sc;
}

// ---------------- shared producer: 16 channels x 4 rows of h1n --------------------
template<int MODE> // 0: rows rg*4+j (kC), 1: rows rg+64*j (kE)
__device__ __forceinline__ void produce16(const float* __restrict__ xd,
                                          const float* __restrict__ a,
                                          int chbase, int rg, int cg,
                                          const float* sW1, const float* ss1,
                                          const float* st1, float (&h)[4][16])
{
  float xv[6][4];
  if (MODE == 0){
    #pragma unroll
    for (int c = 0; c < 3; ++c){
      const float4 t = *(const float4*)&xd[c*R_TOT + chbase + rg*4];
      xv[c][0]=t.x; xv[c][1]=t.y; xv[c][2]=t.z; xv[c][3]=t.w;
    }
    const int qg = (chbase + rg*4) >> 5;
    const int bb = qg >> 11, n = qg & 2047;
    #pragma unroll
    for (int c = 0; c < 3; ++c){
      const float qv = a[(bb*3+c)*NPT + n];
      xv[3+c][0]=qv; xv[3+c][1]=qv; xv[3+c][2]=qv; xv[3+c][3]=qv;
    }
  } else {
    #pragma unroll
    for (int j = 0; j < 4; ++j){
      const int r = chbase + rg + 64*j;
      #pragma unroll
      for (int c = 0; c < 3; ++c) xv[c][j] = xd[c*R_TOT + r];
      const int qg = r >> 5;
      const int bb = qg >> 11, n = qg & 2047;
      #pragma unroll
      for (int c = 0; c < 3; ++c) xv[3+c][j] = a[(bb*3+c)*NPT + n];
    }
  }
  #pragma unroll
  for (int i = 0; i < 16; ++i){
    const int o = cg*16 + i;
    const float w0=sW1[o*6+0], w1=sW1[o*6+1], w2=sW1[o*6+2];
    const float w3=sW1[o*6+3], w4=sW1[o*6+4], w5=sW1[o*6+5];
    const float s = ss1[o], t = st1[o];
    #pragma unroll
    for (int j = 0; j < 4; ++j){
      float acc = xv[0][j]*w0;
      acc = fmaf(xv[1][j], w1, acc); acc = fmaf(xv[2][j], w2, acc);
      acc = fmaf(xv[3][j], w3, acc); acc = fmaf(xv[4][j], w4, acc);
      acc = fmaf(xv[5][j], w5, acc);
      float y = fmaf(acc, s, t);
      h[j][i] = y > 0.f ? y : 0.2f*y;
    }
  }
}

// ---------------- Kernel C: Gram of h1n (MFMA) + mean(h1n) partials ---------------
__global__ __launch_bounds__(256) void kC(const float* __restrict__ xd,
                                          const float* __restrict__ a,
                                          const float* __restrict__ W1,
                                          const float* __restrict__ sb1,
                                          float* __restrict__ Gpart)   // [512][4160]
{
  __shared__ unsigned short hT[64*264];   // [chan][row] bf16, pad 8
  __shared__ float sW1[384], ss1[64], st1[64];
  __shared__ float G[4096];
  const int tid = threadIdx.x, rg = tid & 63, cg = tid >> 6;
  const int l15 = rg & 15, lg = rg >> 4;
  for (int i = tid; i < 384; i += 256) sW1[i] = W1[i];
  if (tid < 64){ ss1[tid] = sb1[tid]; st1[tid] = sb1[64+tid]; }
  __syncthreads();

  f32x4 acc[10];
  #pragma unroll
  for (int i = 0; i < 10; ++i) acc[i] = (f32x4){0.f,0.f,0.f,0.f};
  float mu[16];
  #pragma unroll
  for (int i = 0; i < 16; ++i) mu[i] = 0.f;

  for (int ch = blockIdx.x; ch < NCHUNK; ch += gridDim.x){
    float h[4][16];
    produce16<0>(xd, a, ch*256, rg, cg, sW1, ss1, st1, h);
    #pragma unroll
    for (int i = 0; i < 16; ++i){
      mu[i] += (h[0][i] + h[1][i]) + (h[2][i] + h[3][i]);
      *(int2*)&hT[(cg*16+i)*264 + rg*4] =
          make_int2(pk2(h[0][i],h[1][i]), pk2(h[2][i],h[3][i]));
    }
    __syncthreads();
    #pragma unroll
    for (int s = 0; s < 2; ++s){
      const int kb = cg*64 + s*32 + (lg << 3);
      bf16x8 f0 = *(bf16x8*)&hT[( 0 + l15)*264 + kb];
      bf16x8 f1 = *(bf16x8*)&hT[(16 + l15)*264 + kb];
      bf16x8 f2 = *(bf16x8*)&hT[(32 + l15)*264 + kb];
      bf16x8 f3 = *(bf16x8*)&hT[(48 + l15)*264 + kb];
      acc[0]=MFMA(f0,f0,acc[0]); acc[1]=MFMA(f0,f1,acc[1]);
      acc[2]=MFMA(f0,f2,acc[2]); acc[3]=MFMA(f0,f3,acc[3]);
      acc[4]=MFMA(f1,f1,acc[4]); acc[5]=MFMA(f1,f2,acc[5]);
      acc[6]=MFMA(f1,f3,acc[6]); acc[7]=MFMA(f2,f2,acc[7]);
      acc[8]=MFMA(f2,f3,acc[8]); acc[9]=MFMA(f3,f3,acc[9]);
    }
    __syncthreads();
  }

  for (int i = tid; i < 4096; i += 256) G[i] = 0.f;
  __syncthreads();
  const int TI[10] = {0,0,0,0,1,1,1,2,2,3};
  const int TJ[10] = {0,1,2,3,1,2,3,2,3,3};
  for (int w = 0; w < 4; ++w){
    if (cg == w){
      #pragma unroll
      for (int t = 0; t < 10; ++t){
        const int ti = TI[t], tj = TJ[t];
        #pragma unroll
        for (int j = 0; j < 4; ++j){
          const int gi = ti*16 + lg*4 + j, gj = tj*16 + l15;
          const float v = acc[t][j];
          G[gi*64 + gj] += v;
          if (ti != tj) G[gj*64 + gi] += v;
        }
      }
    }
    __syncthreads();
  }
  #pragma unroll
  for (int i = 0; i < 16; ++i){
    float v = mu[i];
    v += __shfl_down(v,32); v += __shfl_down(v,16); v += __shfl_down(v,8);
    v += __shfl_down(v,4);  v += __shfl_down(v,2);  v += __shfl_down(v,1);
    if (rg == 0) Gpart[blockIdx.x*4160 + 4096 + cg*16 + i] = v;
  }
  for (int i = tid; i < 4096; i += 256) Gpart[blockIdx.x*4160 + i] = G[i];
}

// ---------------- Kernel D1: reduce Gram/mean partials ----------------------------
__global__ __launch_bounds__(256) void kD1(const float* __restrict__ Gpart,
                                           float* __restrict__ Gsum)
{
  const int e = blockIdx.x*256 + threadIdx.x;
  if (e >= 4160) return;
  float s = 0.f;
  for (int bk = 0; bk < 512; ++bk) s += Gpart[bk*4160 + e];
  Gsum[e] = s;
}

// ---------------- Kernel D2: finalize BN2 scale/bias (analytic) -------------------
__global__ __launch_bounds__(64) void kD2(const float* __restrict__ Gsum,
                                          const float* __restrict__ W2,
                                          const float* __restrict__ g2,
                                          const float* __restrict__ b2p,
                                          float* __restrict__ sb2)
{
  const int o = blockIdx.x, j = threadIdx.x;
  const float invR = 1.f / (float)R_TOT;
  const float muj = Gsum[4096 + j]*invR;
  float t = 0.f;
  for (int k = 0; k < 64; ++k){
    float cov = fmaf(-(Gsum[4096 + k]*invR), muj, Gsum[k*64 + j]*invR);
    t = fmaf(W2[o*64 + k], cov, t);
  }
  const float wj = W2[o*64 + j];
  float vpart = wj*t, mpart = wj*muj;
  vpart += __shfl_down(vpart,32); mpart += __shfl_down(mpart,32);
  vpart += __shfl_down(vpart,16); mpart += __shfl_down(mpart,16);
  vpart += __shfl_down(vpart, 8); mpart += __shfl_down(mpart, 8);
  vpart += __shfl_down(vpart, 4); mpart += __shfl_down(mpart, 4);
  vpart += __shfl_down(vpart, 2); mpart += __shfl_down(mpart, 2);
  vpart += __shfl_down(vpart, 1); mpart += __shfl_down(mpart, 1);
  if (j == 0){
    float sc = g2[o] / sqrtf(vpart + 1e-5f);
    sb2[o] = sc; sb2[64+o] = b2p[o] - mpart*sc;
  }
}

// ---------------- Kernel E: layer2 MFMA + BN2 + LReLU + max over K + output -------
__global__ __launch_bounds__(256) void kE(const float* __restrict__ xd,
                                          const float* __restrict__ a,
                                          const float* __restrict__ W1,
                                          const float* __restrict__ sb1,
                                          const float* __restrict__ W2,
                                          const float* __restrict__ sb2,
                                          float* __restrict__ out)
{
  __shared__ unsigned short hN[256*72];   // [row][chan] bf16, pad 8
  __shared__ float sW1[384], ss1[64], st1[64];
  __shared__ float outq[64*8];
  const int tid = threadIdx.x, rg = tid & 63, cg = tid >> 6;
  const int l15 = rg & 15, lg = rg >> 4;
  for (int i = tid; i < 384; i += 256) sW1[i] = W1[i];
  if (tid < 64){ ss1[tid] = sb1[tid]; st1[tid] = sb1[64+tid]; }

  float s2v[4], t2v[4];
  #pragma unroll
  for (int ct = 0; ct < 4; ++ct){ s2v[ct] = sb2[ct*16 + l15]; t2v[ct] = sb2[64 + ct*16 + l15]; }
  bf16x8 bfr[4][2];
  #pragma unroll
  for (int ct = 0; ct < 4; ++ct)
    #pragma unroll
    for (int kk = 0; kk < 2; ++kk){
      const int o = ct*16 + l15, kb = kk*32 + (lg << 3);
      const float4 wa = *(const float4*)&W2[o*64 + kb];
      const float4 wb = *(const float4*)&W2[o*64 + kb + 4];
      int4 t4 = make_int4(pk2(wa.x,wa.y), pk2(wa.z,wa.w), pk2(wb.x,wb.y), pk2(wb.z,wb.w));
      bfr[ct][kk] = __builtin_bit_cast(bf16x8, t4);
    }
  __syncthreads();

  for (int ch = blockIdx.x; ch < NCHUNK; ch += gridDim.x){
    const int bb = ch >> 8, n0 = (ch & 255)*8;
    float h[4][16];
    produce16<1>(xd, a, ch*256, rg, cg, sW1, ss1, st1, h);
    #pragma unroll
    for (int j = 0; j < 4; ++j){
      const int base = (rg + 64*j)*72 + cg*16;
      *(int4*)&hN[base] = make_int4(pk2(h[j][0],h[j][1]), pk2(h[j][2],h[j][3]),
                                    pk2(h[j][4],h[j][5]), pk2(h[j][6],h[j][7]));
      *(int4*)&hN[base+8] = make_int4(pk2(h[j][8],h[j][9]),  pk2(h[j][10],h[j][11]),
                                      pk2(h[j][12],h[j][13]), pk2(h[j][14],h[j][15]));
    }
    __syncthreads();

    f32x4 acc[4][4];
    #pragma unroll
    for (int rt = 0; rt < 4; ++rt)
      #pragma unroll
      for (int ct = 0; ct < 4; ++ct) acc[rt][ct] = (f32x4){0.f,0.f,0.f,0.f};
    #pragma unroll
    for (int kk = 0; kk < 2; ++kk){
      bf16x8 af[4];
      #pragma unroll
      for (int rt = 0; rt < 4; ++rt){
        const int row = cg*64 + rt*16 + l15;
        af[rt] = *(bf16x8*)&hN[row*72 + kk*32 + (lg << 3)];
      }
      #pragma unroll
      for (int rt = 0; rt < 4; ++rt)
        #pragma unroll
        for (int ct = 0; ct < 4; ++ct)
          acc[rt][ct] = MFMA(af[rt], bfr[ct][kk], acc[rt][ct]);
    }

    float qm[2][4];
    #pragma unroll
    for (int q = 0; q < 2; ++q)
      #pragma unroll
      for (int ct = 0; ct < 4; ++ct) qm[q][ct] = -1e30f;
    #pragma unroll
    for (int rt = 0; rt < 4; ++rt)
      #pragma unroll
      for (int ct = 0; ct < 4; ++ct){
        float m1 = -1e30f;
        #pragma unroll
        for (int j = 0; j < 4; ++j){
          float y = fmaf(acc[rt][ct][j], s2v[ct], t2v[ct]);
          y = y > 0.f ? y : 0.2f*y;
          m1 = fmaxf(m1, y);
        }
        m1 = fmaxf(m1, __shfl_xor(m1, 16));
        m1 = fmaxf(m1, __shfl_xor(m1, 32));
        qm[rt>>1][ct] = fmaxf(qm[rt>>1][ct], m1);
      }
    if (lg == 0){
      #pragma unroll
      for (int q = 0; q < 2; ++q)
        #pragma unroll
        for (int ct = 0; ct < 4; ++ct)
          outq[(ct*16 + l15)*8 + cg*2 + q] = qm[q][ct];
    }
    __syncthreads();
    {
      const int o = tid >> 2, qi = tid & 3;
      float2 v; v.x = outq[o*8 + qi*2]; v.y = outq[o*8 + qi*2 + 1];
      *(float2*)&out[(bb*64 + o)*NPT + n0 + qi*2] = v;
    }
    __syncthreads();
  }
}

// ---------------- launch ----------------------------------------------------------
extern "C" void kernel_launch(void* const* d_in, const int* in_sizes, int n_in,
                              void* d_out, int out_size, void* d_ws, size_t ws_size,
                              hipStream_t stream)
{
  const float* a  = (const float*)d_in[0];
  const float* b  = (const float*)d_in[1];
  const float* W1 = (const float*)d_in[2];
  const float* g1 = (const float*)d_in[3];
  const float* b1 = (const float*)d_in[4];
  const float* W2 = (const float*)d_in[5];
  const float* g2 = (const float*)d_in[6];
  const float* b2 = (const float*)d_in[7];
  float* out = (float*)d_out;
  char* ws = (char*)d_ws;
  if (ws_size < 21177600u) return;  // insufficient scratch -> distinct failure signature

  float* xd    = (float*)(ws);                 // 3*R_TOT f32 = 12,582,912 B
  float* sb1   = (float*)(ws + 12640256);      // 128 f32
  float* Gsum  = (float*)(ws + 12640768);      // 4160 f32
  float* sb2   = (float*)(ws + 12657408);      // 128 f32
  float* Gpart = (float*)(ws + 12657920);      // 512*4160 f32 = 8,519,680 B
  float* part1 = Gpart;                        // [2048][28] aliased into Gpart
  float* stsum = Gpart + 2048*28;              // [27] aliased after part1
                                               // (both consumed before kC writes Gpart)

  kA <<<2048, 256, 0, stream>>>(a, b, xd, part1);
  kB0<<<27,  256, 0, stream>>>(part1, stsum);
  kB2<<<1,    64, 0, stream>>>(stsum, W1, g1, b1, sb1);
  kC <<<512, 256, 0, stream>>>(xd, a, W1, sb1, Gpart);
  kD1<<<17,  256, 0, stream>>>(Gpart, Gsum);
  kD2<<<64,  64, 0, stream>>>(Gsum, W2, g2, b2, sb2);
  kE <<<1024, 256, 0, stream>>>(xd, a, W1, sb1, W2, sb2, out);
}

// Round 9
// 287.252 us; speedup vs baseline: 1.0814x; 1.0814x over previous
//
#include <hip/hip_runtime.h>
#include <hip/hip_bf16.h>

#define R_TOT  1048576      // B*N*K = 16*2048*32 rows
#define NPT    2048         // points per batch
#define NCHUNK 4096         // R_TOT / 256

using bf16x8 = __attribute__((ext_vector_type(8))) short;
using f32x4  = __attribute__((ext_vector_type(4))) float;

#define MFMA(A,B,C) __builtin_amdgcn_mfma_f32_16x16x32_bf16((A),(B),(C),0,0,0)

__device__ __forceinline__ unsigned short f2bf(float f){
  unsigned u = __builtin_bit_cast(unsigned, f);
  return (unsigned short)((u + 0x7fffu + ((u >> 16) & 1u)) >> 16);
}
__device__ __forceinline__ unsigned pk2(float lo, float hi){
  return (unsigned)f2bf(lo) | ((unsigned)f2bf(hi) << 16);
}
// order-preserving float->uint (handles negative d2 from fp cancellation)
__device__ __forceinline__ unsigned fu(float f){
  unsigned u = __builtin_bit_cast(unsigned, f);
  return u ^ (0x80000000u | (unsigned)((int)u >> 31));
}

// ---------------- Kernel A: exact 32-NN (16 lanes/query, tiled, tau + mask) -------
__global__ __launch_bounds__(256) void kA(const float* __restrict__ a,
                                          const float* __restrict__ b,
                                          float* __restrict__ xd,     // [3][R_TOT]
                                          float* __restrict__ part1)  // [2048][28]
{
  __shared__ float4 bst[512];        // candidate tile {x,y,z,|b|^2}
  __shared__ int    win[16][33];
  __shared__ int    eqb[16][16];
  __shared__ int    cLT[16], cEQ[16];
  __shared__ float  wstats[4][27];
  const int tid = threadIdx.x;
  const int bb    = blockIdx.x >> 7;           // 128 blocks per batch
  const int qbase = (blockIdx.x & 127) << 4;   // 16 queries per block
  const float* __restrict__ ap = a + bb*3*NPT;
  const float* __restrict__ bp = b + bb*3*NPT;

  const int sub = tid & 15;       // lane within query group
  const int qb  = tid >> 4;       // query within block (0..15)
  const int n   = qbase + qb;
  const float ax = ap[n], ay = ap[NPT+n], az = ap[2*NPT+n];
  const float a2 = (ax*ax + ay*ay) + az*az;

  // pre-zero recovery buffers (OOB armor for the ~1e-4 union-miss case)
  for (int i = tid; i < 16*33; i += 256) (&win[0][0])[i] = 0;
  for (int i = tid; i < 16*16; i += 256) (&eqb[0][0])[i] = 0;
  if (tid < 16){ cLT[tid] = 0; cEQ[tid] = 0; }

  float s[14];
  #pragma unroll
  for (int j = 0; j < 14; ++j) s[j] = 3.0e38f;
  float bd[6]; int cnt = 0;
  float tau;
  unsigned um[4] = {0u, 0u, 0u, 0u};   // per-tile accept masks (static-indexed)

  auto loadTile = [&](int T){
    const int base = T*512;
    for (int i = tid; i < 512; i += 256){
      const float X = bp[base+i], Y = bp[NPT+base+i], Z = bp[2*NPT+base+i];
      bst[i] = make_float4(X, Y, Z, (X*X + Y*Y) + Z*Z);
    }
  };
  auto dist = [&](int li)->float{
    const float4 bc = bst[li];
    const float dot = fmaf(az, bc.z, fmaf(ay, bc.y, ax*bc.x));
    return fmaf(-2.f, dot, a2 + bc.w);
  };
  auto insert = [&](float d){   // sorted ascending, drop current max
    #pragma unroll
    for (int j = 13; j >= 1; --j){
      const bool cj  = d < s[j];
      const bool cj1 = d < s[j-1];
      s[j] = cj ? (cj1 ? s[j-1] : d) : s[j];
    }
    s[0] = fminf(s[0], d);
  };
  auto flush = [&](){
    #pragma unroll
    for (int t = 0; t < 6; ++t){
      if (t < cnt && bd[t] < s[13]) insert(bd[t]);
    }
    cnt = 0;
  };

  // ---- tile 0 + tau seed (max of first 64 group candidates >= running 32nd) ----
  loadTile(0);
  __syncthreads();
  {
    float m = dist(sub);
    m = fmaxf(m, dist(sub + 16));
    m = fmaxf(m, dist(sub + 32));
    m = fmaxf(m, dist(sub + 48));
    m = fmaxf(m, __shfl_xor(m, 1));
    m = fmaxf(m, __shfl_xor(m, 2));
    m = fmaxf(m, __shfl_xor(m, 4));
    m = fmaxf(m, __shfl_xor(m, 8));
    tau = m;
  }

  // ---- filtered scan over 4 tiles (records accept bits) ----
  #pragma unroll
  for (int T = 0; T < 4; ++T){
    if (T){ __syncthreads(); loadTile(T); __syncthreads(); }
    for (int jj = 0; jj < 32; jj += 4){
      #pragma unroll
      for (int u = 0; u < 4; ++u){
        const int li = sub + ((jj + u) << 4);
        const float d = dist(li);
        if (d <= tau && d < s[13]){
          #pragma unroll
          for (int t2 = 0; t2 < 6; ++t2) if (cnt == t2) bd[t2] = d;
          ++cnt;
          um[T] |= 1u << (jj + u);
        }
      }
      if (__any(cnt > 2)) flush();
      if ((jj & 12) == 12){   // refresh tau twice per tile: group-max of s[1]
        float m = s[1];
        m = fmaxf(m, __shfl_xor(m, 1));
        m = fmaxf(m, __shfl_xor(m, 2));
        m = fmaxf(m, __shfl_xor(m, 4));
        m = fmaxf(m, __shfl_xor(m, 8));
        tau = fminf(tau, m);
      }
    }
  }
  flush();

  // ---- exact 32nd value via bracketed uint bisection over retained values ----
  unsigned du[14];
  #pragma unroll
  for (int j = 0; j < 14; ++j) du[j] = fu(s[j]);
  unsigned lo, hi;
  {
    unsigned mn = du[0];
    mn = min(mn, (unsigned)__shfl_xor((int)mn, 1));
    mn = min(mn, (unsigned)__shfl_xor((int)mn, 2));
    mn = min(mn, (unsigned)__shfl_xor((int)mn, 4));
    mn = min(mn, (unsigned)__shfl_xor((int)mn, 8));
    unsigned mx1 = du[1];
    mx1 = max(mx1, (unsigned)__shfl_xor((int)mx1, 1));
    mx1 = max(mx1, (unsigned)__shfl_xor((int)mx1, 2));
    mx1 = max(mx1, (unsigned)__shfl_xor((int)mx1, 4));
    mx1 = max(mx1, (unsigned)__shfl_xor((int)mx1, 8));
    lo = mn; hi = mx1 + 1u;
  }
  while (__any(hi - lo > 1u)){
    const unsigned mid = lo + ((hi - lo) >> 1);
    int cl = 0;
    #pragma unroll
    for (int j = 0; j < 14; ++j) cl += (du[j] < mid) ? 1 : 0;
    cl += __shfl_xor(cl, 1); cl += __shfl_xor(cl, 2);
    cl += __shfl_xor(cl, 4); cl += __shfl_xor(cl, 8);
    if (cl >= 32) hi = mid; else lo = mid;
  }
  const unsigned ustar = lo;

  // ---- index recovery: reload tiles, but only accepted bits (~6/lane total) ----
  #pragma unroll
  for (int T = 0; T < 4; ++T){
    __syncthreads();
    loadTile(T);
    __syncthreads();
    unsigned m = um[T];
    while (m){
      const int k = __ffs(m) - 1; m &= m - 1u;
      const int li = sub + (k << 4);
      const unsigned ud = fu(dist(li));
      if (ud < ustar){
        const int slot = atomicAdd(&cLT[qb], 1);
        if (slot < 32) win[qb][slot] = T*512 + li;
      } else if (ud == ustar){
        const int slot = atomicAdd(&cEQ[qb], 1);
        if (slot < 16) eqb[qb][slot] = T*512 + li;
      }
    }
  }
  __syncthreads();

  // ---- boundary fill (lowest-index equals, matches stable top_k) ----
  if (sub == 0){
    const int c1 = cLT[qb] < 32 ? cLT[qb] : 32;
    const int totEQ = cEQ[qb];
    const int need = 32 - c1;
    const int stored = totEQ < 16 ? totEQ : 16;
    if (totEQ == need){
      const int lim = need < stored ? need : stored;
      for (int e = 0; e < lim; ++e) win[qb][c1 + e] = eqb[qb][e];
      for (int e = lim; e < need; ++e) win[qb][c1 + e] = eqb[qb][0];
    } else {
      int last = -1;
      for (int r = 0; r < need; ++r){
        int mm = 0x7FFFFFFF;
        for (int e = 0; e < stored; ++e){
          const int v = eqb[qb][e];
          if (v > last && v < mm) mm = v;
        }
        if (mm == 0x7FFFFFFF) mm = eqb[qb][0];
        win[qb][c1 + r] = mm; last = mm;
      }
    }
  }
  __syncthreads();

  // ---- diffs (2 winners per lane) + distributive stats partials ----
  float sdx=0,sdy=0,sdz=0,gxx=0,gxy=0,gxz=0,gyy=0,gyz=0,gzz=0;
  const int rbase = (bb*NPT + n) * 32;
  float ox[2], oy[2], oz[2];
  #pragma unroll
  for (int r = 0; r < 2; ++r){
    const int w = win[qb][sub*2 + r];
    const float dx = ap[w] - ax, dy = ap[NPT+w] - ay, dz = ap[2*NPT+w] - az;
    ox[r]=dx; oy[r]=dy; oz[r]=dz;
    sdx += dx; sdy += dy; sdz += dz;
    gxx = fmaf(dx,dx,gxx); gxy = fmaf(dx,dy,gxy); gxz = fmaf(dx,dz,gxz);
    gyy = fmaf(dy,dy,gyy); gyz = fmaf(dy,dz,gyz); gzz = fmaf(dz,dz,gzz);
  }
  *(float2*)&xd[0*R_TOT + rbase + sub*2] = make_float2(ox[0],ox[1]);
  *(float2*)&xd[1*R_TOT + rbase + sub*2] = make_float2(oy[0],oy[1]);
  *(float2*)&xd[2*R_TOT + rbase + sub*2] = make_float2(oz[0],oz[1]);

  float S[27];
  S[0]=sdx; S[1]=sdy; S[2]=sdz; S[3]=2.f*ax; S[4]=2.f*ay; S[5]=2.f*az;
  S[6]=gxx; S[7]=gxy; S[8]=gxz; S[9]=sdx*ax; S[10]=sdx*ay; S[11]=sdx*az;
  S[12]=gyy; S[13]=gyz; S[14]=sdy*ax; S[15]=sdy*ay; S[16]=sdy*az;
  S[17]=gzz; S[18]=sdz*ax; S[19]=sdz*ay; S[20]=sdz*az;
  S[21]=2.f*ax*ax; S[22]=2.f*ax*ay; S[23]=2.f*ax*az;
  S[24]=2.f*ay*ay; S[25]=2.f*ay*az; S[26]=2.f*az*az;
  #pragma unroll
  for (int i = 0; i < 27; ++i){
    float v = S[i];
    v += __shfl_down(v,32); v += __shfl_down(v,16); v += __shfl_down(v,8);
    v += __shfl_down(v,4);  v += __shfl_down(v,2);  v += __shfl_down(v,1);
    if ((tid & 63) == 0) wstats[tid>>6][i] = v;
  }
  __syncthreads();
  if (tid < 27)
    part1[blockIdx.x*28 + tid] = (wstats[0][tid]+wstats[1][tid]) + (wstats[2][tid]+wstats[3][tid]);
}

// ---------------- Kernel B0: reduce part1 over 2048 blocks ------------------------
__global__ __launch_bounds__(256) void kB0(const float* __restrict__ part1,
                                           float* __restrict__ st)   // [27]
{
  __shared__ float red[256];
  const int i = blockIdx.x;  // 0..26
  float ssum = 0.f;
  for (int k = threadIdx.x; k < 2048; k += 256) ssum += part1[k*28 + i];
  red[threadIdx.x] = ssum;
  __syncthreads();
  for (int w = 128; w > 0; w >>= 1){
    if (threadIdx.x < w) red[threadIdx.x] += red[threadIdx.x + w];
    __syncthreads();
  }
  if (threadIdx.x == 0) st[i] = red[0];
}

// ---------------- Kernel B2: finalize BN1 scale/bias (analytic) -------------------
__global__ __launch_bounds__(64) void kB2(const float* __restrict__ st_in,
                                          const float* __restrict__ W1,
                                          const float* __restrict__ g1,
                                          const float* __restrict__ b1,
                                          float* __restrict__ sb1)
{
  __shared__ float st[27];
  const int tid = threadIdx.x;
  if (tid < 27) st[tid] = st_in[tid];
  __syncthreads();
  const int o = tid;
  const float invR = 1.f / (float)R_TOT;
  float mu[6], w[6];
  #pragma unroll
  for (int c = 0; c < 6; ++c){ mu[c] = st[c]*invR; w[c] = W1[o*6+c]; }
  float mean = 0.f;
  #pragma unroll
  for (int c = 0; c < 6; ++c) mean = fmaf(w[c], mu[c], mean);
  float var = 0.f;
  #pragma unroll
  for (int c = 0; c < 6; ++c)
    #pragma unroll
    for (int c2 = 0; c2 < 6; ++c2){
      const int lo = c < c2 ? c : c2, hi = c < c2 ? c2 : c;
      const int ti = 6*lo - lo*(lo-1)/2 + (hi - lo);
      float cov = st[6+ti]*invR - mu[c]*mu[c2];
      var = fmaf(w[c]*w[c2], cov, var);
    }
  float sc = g1[o] / sqrtf(var + 1e-5f);
  sb1[o] = sc; sb1[64+o] = b1[o] - mean*sc;
}

// ---------------- shared producer: 16 channels x 4 rows of h1n --------------------
template<int MODE> // 0: rows rg*4+j (kC), 1: rows rg+64*j (kE)
__device__ __forceinline__ void produce16(const float* __restrict__ xd,
                                          const float* __restrict__ a,
                                          int chbase, int rg, int cg,
                                          const float* sW1, const float* ss1,
                                          const float* st1, float (&h)[4][16])
{
  float xv[6][4];
  if (MODE == 0){
    #pragma unroll
    for (int c = 0; c < 3; ++c){
      const float4 t = *(const float4*)&xd[c*R_TOT + chbase + rg*4];
      xv[c][0]=t.x; xv[c][1]=t.y; xv[c][2]=t.z; xv[c][3]=t.w;
    }
    const int qg = (chbase + rg*4) >> 5;
    const int bb = qg >> 11, n = qg & 2047;
    #pragma unroll
    for (int c = 0; c < 3; ++c){
      const float qv = a[(bb*3+c)*NPT + n];
      xv[3+c][0]=qv; xv[3+c][1]=qv; xv[3+c][2]=qv; xv[3+c][3]=qv;
    }
  } else {
    #pragma unroll
    for (int j = 0; j < 4; ++j){
      const int r = chbase + rg + 64*j;
      #pragma unroll
      for (int c = 0; c < 3; ++c) xv[c][j] = xd[c*R_TOT + r];
      const int qg = r >> 5;
      const int bb = qg >> 11, n = qg & 2047;
      #pragma unroll
      for (int c = 0; c < 3; ++c) xv[3+c][j] = a[(bb*3+c)*NPT + n];
    }
  }
  #pragma unroll
  for (int i = 0; i < 16; ++i){
    const int o = cg*16 + i;
    const float w0=sW1[o*6+0], w1=sW1[o*6+1], w2=sW1[o*6+2];
    const float w3=sW1[o*6+3], w4=sW1[o*6+4], w5=sW1[o*6+5];
    const float s = ss1[o], t = st1[o];
    #pragma unroll
    for (int j = 0; j < 4; ++j){
      float acc = xv[0][j]*w0;
      acc = fmaf(xv[1][j], w1, acc); acc = fmaf(xv[2][j], w2, acc);
      acc = fmaf(xv[3][j], w3, acc); acc = fmaf(xv[4][j], w4, acc);
      acc = fmaf(xv[5][j], w5, acc);
      float y = fmaf(acc, s, t);
      h[j][i] = y > 0.f ? y : 0.2f*y;
    }
  }
}

// ---------------- Kernel C: Gram of h1n (MFMA) + mean(h1n) partials ---------------
__global__ __launch_bounds__(256) void kC(const float* __restrict__ xd,
                                          const float* __restrict__ a,
                                          const float* __restrict__ W1,
                                          const float* __restrict__ sb1,
                                          float* __restrict__ Gpart)   // [512][4160]
{
  __shared__ unsigned short hT[64*264];   // [chan][row] bf16, pad 8
  __shared__ float sW1[384], ss1[64], st1[64];
  __shared__ float G[4096];
  const int tid = threadIdx.x, rg = tid & 63, cg = tid >> 6;
  const int l15 = rg & 15, lg = rg >> 4;
  for (int i = tid; i < 384; i += 256) sW1[i] = W1[i];
  if (tid < 64){ ss1[tid] = sb1[tid]; st1[tid] = sb1[64+tid]; }
  __syncthreads();

  f32x4 acc[10];
  #pragma unroll
  for (int i = 0; i < 10; ++i) acc[i] = (f32x4){0.f,0.f,0.f,0.f};
  float mu[16];
  #pragma unroll
  for (int i = 0; i < 16; ++i) mu[i] = 0.f;

  for (int ch = blockIdx.x; ch < NCHUNK; ch += gridDim.x){
    float h[4][16];
    produce16<0>(xd, a, ch*256, rg, cg, sW1, ss1, st1, h);
    #pragma unroll
    for (int i = 0; i < 16; ++i){
      mu[i] += (h[0][i] + h[1][i]) + (h[2][i] + h[3][i]);
      *(int2*)&hT[(cg*16+i)*264 + rg*4] =
          make_int2(pk2(h[0][i],h[1][i]), pk2(h[2][i],h[3][i]));
    }
    __syncthreads();
    #pragma unroll
    for (int s = 0; s < 2; ++s){
      const int kb = cg*64 + s*32 + (lg << 3);
      bf16x8 f0 = *(bf16x8*)&hT[( 0 + l15)*264 + kb];
      bf16x8 f1 = *(bf16x8*)&hT[(16 + l15)*264 + kb];
      bf16x8 f2 = *(bf16x8*)&hT[(32 + l15)*264 + kb];
      bf16x8 f3 = *(bf16x8*)&hT[(48 + l15)*264 + kb];
      acc[0]=MFMA(f0,f0,acc[0]); acc[1]=MFMA(f0,f1,acc[1]);
      acc[2]=MFMA(f0,f2,acc[2]); acc[3]=MFMA(f0,f3,acc[3]);
      acc[4]=MFMA(f1,f1,acc[4]); acc[5]=MFMA(f1,f2,acc[5]);
      acc[6]=MFMA(f1,f3,acc[6]); acc[7]=MFMA(f2,f2,acc[7]);
      acc[8]=MFMA(f2,f3,acc[8]); acc[9]=MFMA(f3,f3,acc[9]);
    }
    __syncthreads();
  }

  for (int i = tid; i < 4096; i += 256) G[i] = 0.f;
  __syncthreads();
  const int TI[10] = {0,0,0,0,1,1,1,2,2,3};
  const int TJ[10] = {0,1,2,3,1,2,3,2,3,3};
  for (int w = 0; w < 4; ++w){
    if (cg == w){
      #pragma unroll
      for (int t = 0; t < 10; ++t){
        const int ti = TI[t], tj = TJ[t];
        #pragma unroll
        for (int j = 0; j < 4; ++j){
          const int gi = ti*16 + lg*4 + j, gj = tj*16 + l15;
          const float v = acc[t][j];
          G[gi*64 + gj] += v;
          if (ti != tj) G[gj*64 + gi] += v;
        }
      }
    }
    __syncthreads();
  }
  #pragma unroll
  for (int i = 0; i < 16; ++i){
    float v = mu[i];
    v += __shfl_down(v,32); v += __shfl_down(v,16); v += __shfl_down(v,8);
    v += __shfl_down(v,4);  v += __shfl_down(v,2);  v += __shfl_down(v,1);
    if (rg == 0) Gpart[blockIdx.x*4160 + 4096 + cg*16 + i] = v;
  }
  for (int i = tid; i < 4096; i += 256) Gpart[blockIdx.x*4160 + i] = G[i];
}

// ---------------- Kernel D1: reduce Gram/mean partials ----------------------------
__global__ __launch_bounds__(256) void kD1(const float* __restrict__ Gpart,
                                           float* __restrict__ Gsum)
{
  const int e = blockIdx.x*256 + threadIdx.x;
  if (e >= 4160) return;
  float s = 0.f;
  for (int bk = 0; bk < 512; ++bk) s += Gpart[bk*4160 + e];
  Gsum[e] = s;
}

// ---------------- Kernel D2: finalize BN2 scale/bias (analytic) -------------------
__global__ __launch_bounds__(64) void kD2(const float* __restrict__ Gsum,
                                          const float* __restrict__ W2,
                                          const float* __restrict__ g2,
                                          const float* __restrict__ b2p,
                                          float* __restrict__ sb2)
{
  const int o = blockIdx.x, j = threadIdx.x;
  const float invR = 1.f / (float)R_TOT;
  const float muj = Gsum[4096 + j]*invR;
  float t = 0.f;
  for (int k = 0; k < 64; ++k){
    float cov = fmaf(-(Gsum[4096 + k]*invR), muj, Gsum[k*64 + j]*invR);
    t = fmaf(W2[o*64 + k], cov, t);
  }
  const float wj = W2[o*64 + j];
  float vpart = wj*t, mpart = wj*muj;
  vpart += __shfl_down(vpart,32); mpart += __shfl_down(mpart,32);
  vpart += __shfl_down(vpart,16); mpart += __shfl_down(mpart,16);
  vpart += __shfl_down(vpart, 8); mpart += __shfl_down(mpart, 8);
  vpart += __shfl_down(vpart, 4); mpart += __shfl_down(mpart, 4);
  vpart += __shfl_down(vpart, 2); mpart += __shfl_down(mpart, 2);
  vpart += __shfl_down(vpart, 1); mpart += __shfl_down(mpart, 1);
  if (j == 0){
    float sc = g2[o] / sqrtf(vpart + 1e-5f);
    sb2[o] = sc; sb2[64+o] = b2p[o] - mpart*sc;
  }
}

// ---------------- Kernel E: layer2 MFMA + BN2 + LReLU + max over K + output -------
__global__ __launch_bounds__(256) void kE(const float* __restrict__ xd,
                                          const float* __restrict__ a,
                                          const float* __restrict__ W1,
                                          const float* __restrict__ sb1,
                                          const float* __restrict__ W2,
                                          const float* __restrict__ sb2,
                                          float* __restrict__ out)
{
  __shared__ unsigned short hN[256*72];   // [row][chan] bf16, pad 8
  __shared__ float sW1[384], ss1[64], st1[64];
  __shared__ float outq[64*8];
  const int tid = threadIdx.x, rg = tid & 63, cg = tid >> 6;
  const int l15 = rg & 15, lg = rg >> 4;
  for (int i = tid; i < 384; i += 256) sW1[i] = W1[i];
  if (tid < 64){ ss1[tid] = sb1[tid]; st1[tid] = sb1[64+tid]; }

  float s2v[4], t2v[4];
  #pragma unroll
  for (int ct = 0; ct < 4; ++ct){ s2v[ct] = sb2[ct*16 + l15]; t2v[ct] = sb2[64 + ct*16 + l15]; }
  bf16x8 bfr[4][2];
  #pragma unroll
  for (int ct = 0; ct < 4; ++ct)
    #pragma unroll
    for (int kk = 0; kk < 2; ++kk){
      const int o = ct*16 + l15, kb = kk*32 + (lg << 3);
      const float4 wa = *(const float4*)&W2[o*64 + kb];
      const float4 wb = *(const float4*)&W2[o*64 + kb + 4];
      int4 t4 = make_int4(pk2(wa.x,wa.y), pk2(wa.z,wa.w), pk2(wb.x,wb.y), pk2(wb.z,wb.w));
      bfr[ct][kk] = __builtin_bit_cast(bf16x8, t4);
    }
  __syncthreads();

  for (int ch = blockIdx.x; ch < NCHUNK; ch += gridDim.x){
    const int bb = ch >> 8, n0 = (ch & 255)*8;
    float h[4][16];
    produce16<1>(xd, a, ch*256, rg, cg, sW1, ss1, st1, h);
    #pragma unroll
    for (int j = 0; j < 4; ++j){
      const int base = (rg + 64*j)*72 + cg*16;
      *(int4*)&hN[base] = make_int4(pk2(h[j][0],h[j][1]), pk2(h[j][2],h[j][3]),
                                    pk2(h[j][4],h[j][5]), pk2(h[j][6],h[j][7]));
      *(int4*)&hN[base+8] = make_int4(pk2(h[j][8],h[j][9]),  pk2(h[j][10],h[j][11]),
                                      pk2(h[j][12],h[j][13]), pk2(h[j][14],h[j][15]));
    }
    __syncthreads();

    f32x4 acc[4][4];
    #pragma unroll
    for (int rt = 0; rt < 4; ++rt)
      #pragma unroll
      for (int ct = 0; ct < 4; ++ct) acc[rt][ct] = (f32x4){0.f,0.f,0.f,0.f};
    #pragma unroll
    for (int kk = 0; kk < 2; ++kk){
      bf16x8 af[4];
      #pragma unroll
      for (int rt = 0; rt < 4; ++rt){
        const int row = cg*64 + rt*16 + l15;
        af[rt] = *(bf16x8*)&hN[row*72 + kk*32 + (lg << 3)];
      }
      #pragma unroll
      for (int rt = 0; rt < 4; ++rt)
        #pragma unroll
        for (int ct = 0; ct < 4; ++ct)
          acc[rt][ct] = MFMA(af[rt], bfr[ct][kk], acc[rt][ct]);
    }

    float qm[2][4];
    #pragma unroll
    for (int q = 0; q < 2; ++q)
      #pragma unroll
      for (int ct = 0; ct < 4; ++ct) qm[q][ct] = -1e30f;
    #pragma unroll
    for (int rt = 0; rt < 4; ++rt)
      #pragma unroll
      for (int ct = 0; ct < 4; ++ct){
        float m1 = -1e30f;
        #pragma unroll
        for (int j = 0; j < 4; ++j){
          float y = fmaf(acc[rt][ct][j], s2v[ct], t2v[ct]);
          y = y > 0.f ? y : 0.2f*y;
          m1 = fmaxf(m1, y);
        }
        m1 = fmaxf(m1, __shfl_xor(m1, 16));
        m1 = fmaxf(m1, __shfl_xor(m1, 32));
        qm[rt>>1][ct] = fmaxf(qm[rt>>1][ct], m1);
      }
    if (lg == 0){
      #pragma unroll
      for (int q = 0; q < 2; ++q)
        #pragma unroll
        for (int ct = 0; ct < 4; ++ct)
          outq[(ct*16 + l15)*8 + cg*2 + q] = qm[q][ct];
    }
    __syncthreads();
    {
      const int o = tid >> 2, qi = tid & 3;
      float2 v; v.x = outq[o*8 + qi*2]; v.y = outq[o*8 + qi*2 + 1];
      *(float2*)&out[(bb*64 + o)*NPT + n0 + qi*2] = v;
    }
    __syncthreads();
  }
}

// ---------------- launch ----------------------------------------------------------
extern "C" void kernel_launch(void* const* d_in, const int* in_sizes, int n_in,
                              void* d_out, int out_size, void* d_ws, size_t ws_size,
                              hipStream_t stream)
{
  const float* a  = (const float*)d_in[0];
  const float* b  = (const float*)d_in[1];
  const float* W1 = (const float*)d_in[2];
  const float* g1 = (const float*)d_in[3];
  const float* b1 = (const float*)d_in[4];
  const float* W2 = (const float*)d_in[5];
  const float* g2 = (const float*)d_in[6];
  const float* b2 = (const float*)d_in[7];
  float* out = (float*)d_out;
  char* ws = (char*)d_ws;
  if (ws_size < 21177600u) return;  // insufficient scratch -> distinct failure signature

  float* xd    = (float*)(ws);                 // 3*R_TOT f32 = 12,582,912 B
  float* sb1   = (float*)(ws + 12640256);      // 128 f32
  float* Gsum  = (float*)(ws + 12640768);      // 4160 f32
  float* sb2   = (float*)(ws + 12657408);      // 128 f32
  float* Gpart = (float*)(ws + 12657920);      // 512*4160 f32 = 8,519,680 B
  float* part1 = Gpart;                        // [2048][28] aliased into Gpart
  float* stsum = Gpart + 2048*28;              // [27] aliased after part1
                                               // (both consumed before kC writes Gpart)

  kA <<<2048, 256, 0, stream>>>(a, b, xd, part1);
  kB0<<<27,  256, 0, stream>>>(part1, stsum);
  kB2<<<1,    64, 0, stream>>>(stsum, W1, g1, b1, sb1);
  kC <<<512, 256, 0, stream>>>(xd, a, W1, sb1, Gpart);
  kD1<<<17,  256, 0, stream>>>(Gpart, Gsum);
  kD2<<<64,  64, 0, stream>>>(Gsum, W2, g2, b2, sb2);
  kE <<<1024, 256, 0, stream>>>(xd, a, W1, sb1, W2, sb2, out);
}

// Round 10
// 270.337 us; speedup vs baseline: 1.1491x; 1.0626x over previous
//
#include <hip/hip_runtime.h>
#include <hip/hip_bf16.h>

#define R_TOT  1048576      // B*N*K = 16*2048*32 rows
#define NPT    2048         // points per batch
#define NCHUNK 4096         // R_TOT / 256

using bf16x8 = __attribute__((ext_vector_type(8))) short;
using f32x4  = __attribute__((ext_vector_type(4))) float;

#define MFMA(A,B,C) __builtin_amdgcn_mfma_f32_16x16x32_bf16((A),(B),(C),0,0,0)

__device__ __forceinline__ unsigned short f2bf(float f){
  unsigned u = __builtin_bit_cast(unsigned, f);
  return (unsigned short)((u + 0x7fffu + ((u >> 16) & 1u)) >> 16);
}
__device__ __forceinline__ unsigned pk2(float lo, float hi){
  return (unsigned)f2bf(lo) | ((unsigned)f2bf(hi) << 16);
}
// order-preserving float->uint (handles negative d2 from fp cancellation)
__device__ __forceinline__ unsigned fu(float f){
  unsigned u = __builtin_bit_cast(unsigned, f);
  return u ^ (0x80000000u | (unsigned)((int)u >> 31));
}

// ---------------- Kernel A: exact 32-NN (16 lanes/query, tiled, tau + mask) -------
__global__ __launch_bounds__(256) void kA(const float* __restrict__ a,
                                          const float* __restrict__ b,
                                          float* __restrict__ xd,     // [3][R_TOT]
                                          float* __restrict__ part1)  // [2048][28]
{
  __shared__ float4 bst[512];        // candidate tile {x,y,z,|b|^2}
  __shared__ int    win[16][33];
  __shared__ int    eqb[16][16];
  __shared__ int    cLT[16], cEQ[16];
  __shared__ float  wstats[4][27];
  const int tid = threadIdx.x;
  const int bb    = blockIdx.x >> 7;           // 128 blocks per batch
  const int qbase = (blockIdx.x & 127) << 4;   // 16 queries per block
  const float* __restrict__ ap = a + bb*3*NPT;
  const float* __restrict__ bp = b + bb*3*NPT;

  const int sub = tid & 15;       // lane within query group
  const int qb  = tid >> 4;       // query within block (0..15)
  const int n   = qbase + qb;
  const float ax = ap[n], ay = ap[NPT+n], az = ap[2*NPT+n];
  const float a2 = (ax*ax + ay*ay) + az*az;

  // pre-zero recovery buffers (OOB armor for the rare union-miss case)
  for (int i = tid; i < 16*33; i += 256) (&win[0][0])[i] = 0;
  for (int i = tid; i < 16*16; i += 256) (&eqb[0][0])[i] = 0;
  if (tid < 16){ cLT[tid] = 0; cEQ[tid] = 0; }

  float s[12];
  #pragma unroll
  for (int j = 0; j < 12; ++j) s[j] = 3.0e38f;
  float bd[6]; int cnt = 0;
  float tau;
  unsigned um[4] = {0u, 0u, 0u, 0u};   // per-tile accept masks (static-indexed)

  auto loadTile = [&](int T){
    const int base = T*512;
    for (int i = tid; i < 512; i += 256){
      const float X = bp[base+i], Y = bp[NPT+base+i], Z = bp[2*NPT+base+i];
      bst[i] = make_float4(X, Y, Z, (X*X + Y*Y) + Z*Z);
    }
  };
  auto dist = [&](int li)->float{
    const float4 bc = bst[li];
    const float dot = fmaf(az, bc.z, fmaf(ay, bc.y, ax*bc.x));
    return fmaf(-2.f, dot, a2 + bc.w);
  };
  auto insert = [&](float d){   // sorted ascending, drop current max
    #pragma unroll
    for (int j = 11; j >= 1; --j){
      const bool cj  = d < s[j];
      const bool cj1 = d < s[j-1];
      s[j] = cj ? (cj1 ? s[j-1] : d) : s[j];
    }
    s[0] = fminf(s[0], d);
  };
  auto flush = [&](){
    #pragma unroll
    for (int t = 0; t < 6; ++t){
      if (t < cnt && bd[t] < s[11]) insert(bd[t]);
    }
    cnt = 0;
  };

  // ---- tile 0 + tau seed: per-lane smallest-2 of 8 samples, group-max of s1 ----
  // validity: 2 elements/lane <= s1 -> 32 elements <= group-max >= 32nd smallest
  loadTile(0);
  __syncthreads();
  {
    float s0 = 3.0e38f, s1 = 3.0e38f;
    #pragma unroll
    for (int k = 0; k < 8; ++k){
      const float d = dist(sub + (k << 4));
      const bool c1 = d < s1;
      const bool c0 = d < s0;
      s1 = c1 ? (c0 ? s0 : d) : s1;
      s0 = fminf(s0, d);
    }
    float m = s1;
    m = fmaxf(m, __shfl_xor(m, 1));
    m = fmaxf(m, __shfl_xor(m, 2));
    m = fmaxf(m, __shfl_xor(m, 4));
    m = fmaxf(m, __shfl_xor(m, 8));
    tau = m;
  }

  // ---- filtered scan over 4 tiles (records accept bits) ----
  #pragma unroll
  for (int T = 0; T < 4; ++T){
    if (T){ __syncthreads(); loadTile(T); __syncthreads(); }
    for (int jj = 0; jj < 32; jj += 4){
      #pragma unroll
      for (int u = 0; u < 4; ++u){
        const int li = sub + ((jj + u) << 4);
        const float d = dist(li);
        if (d <= tau && d < s[11]){
          #pragma unroll
          for (int t2 = 0; t2 < 6; ++t2) if (cnt == t2) bd[t2] = d;
          ++cnt;
          um[T] |= 1u << (jj + u);
        }
      }
      if (__any(cnt > 2)) flush();
      if ((jj & 4) == 4){   // refresh tau 4x per tile: group-max of s[1]
        float m = s[1];
        m = fmaxf(m, __shfl_xor(m, 1));
        m = fmaxf(m, __shfl_xor(m, 2));
        m = fmaxf(m, __shfl_xor(m, 4));
        m = fmaxf(m, __shfl_xor(m, 8));
        tau = fminf(tau, m);
      }
    }
  }
  flush();

  // ---- exact 32nd value via bracketed uint bisection over retained values ----
  unsigned du[12];
  #pragma unroll
  for (int j = 0; j < 12; ++j) du[j] = fu(s[j]);
  unsigned lo, hi;
  {
    unsigned mn = du[0];
    mn = min(mn, (unsigned)__shfl_xor((int)mn, 1));
    mn = min(mn, (unsigned)__shfl_xor((int)mn, 2));
    mn = min(mn, (unsigned)__shfl_xor((int)mn, 4));
    mn = min(mn, (unsigned)__shfl_xor((int)mn, 8));
    unsigned mx1 = du[1];
    mx1 = max(mx1, (unsigned)__shfl_xor((int)mx1, 1));
    mx1 = max(mx1, (unsigned)__shfl_xor((int)mx1, 2));
    mx1 = max(mx1, (unsigned)__shfl_xor((int)mx1, 4));
    mx1 = max(mx1, (unsigned)__shfl_xor((int)mx1, 8));
    lo = mn; hi = mx1 + 1u;
  }
  while (__any(hi - lo > 1u)){
    const unsigned mid = lo + ((hi - lo) >> 1);
    int cl = 0;
    #pragma unroll
    for (int j = 0; j < 12; ++j) cl += (du[j] < mid) ? 1 : 0;
    cl += __shfl_xor(cl, 1); cl += __shfl_xor(cl, 2);
    cl += __shfl_xor(cl, 4); cl += __shfl_xor(cl, 8);
    if (cl >= 32) hi = mid; else lo = mid;
  }
  const unsigned ustar = lo;

  // ---- index recovery: reload tiles, but only accepted bits (~6/lane total) ----
  #pragma unroll
  for (int T = 0; T < 4; ++T){
    __syncthreads();
    loadTile(T);
    __syncthreads();
    unsigned m = um[T];
    while (m){
      const int k = __ffs(m) - 1; m &= m - 1u;
      const int li = sub + (k << 4);
      const unsigned ud = fu(dist(li));
      if (ud < ustar){
        const int slot = atomicAdd(&cLT[qb], 1);
        if (slot < 32) win[qb][slot] = T*512 + li;
      } else if (ud == ustar){
        const int slot = atomicAdd(&cEQ[qb], 1);
        if (slot < 16) eqb[qb][slot] = T*512 + li;
      }
    }
  }
  __syncthreads();

  // ---- boundary fill (lowest-index equals, matches stable top_k) ----
  if (sub == 0){
    const int c1 = cLT[qb] < 32 ? cLT[qb] : 32;
    const int totEQ = cEQ[qb];
    const int need = 32 - c1;
    const int stored = totEQ < 16 ? totEQ : 16;
    if (totEQ == need){
      const int lim = need < stored ? need : stored;
      for (int e = 0; e < lim; ++e) win[qb][c1 + e] = eqb[qb][e];
      for (int e = lim; e < need; ++e) win[qb][c1 + e] = eqb[qb][0];
    } else {
      int last = -1;
      for (int r = 0; r < need; ++r){
        int mm = 0x7FFFFFFF;
        for (int e = 0; e < stored; ++e){
          const int v = eqb[qb][e];
          if (v > last && v < mm) mm = v;
        }
        if (mm == 0x7FFFFFFF) mm = eqb[qb][0];
        win[qb][c1 + r] = mm; last = mm;
      }
    }
  }
  __syncthreads();

  // ---- diffs (2 winners per lane) + distributive stats partials ----
  float sdx=0,sdy=0,sdz=0,gxx=0,gxy=0,gxz=0,gyy=0,gyz=0,gzz=0;
  const int rbase = (bb*NPT + n) * 32;
  float ox[2], oy[2], oz[2];
  #pragma unroll
  for (int r = 0; r < 2; ++r){
    const int w = win[qb][sub*2 + r];
    const float dx = ap[w] - ax, dy = ap[NPT+w] - ay, dz = ap[2*NPT+w] - az;
    ox[r]=dx; oy[r]=dy; oz[r]=dz;
    sdx += dx; sdy += dy; sdz += dz;
    gxx = fmaf(dx,dx,gxx); gxy = fmaf(dx,dy,gxy); gxz = fmaf(dx,dz,gxz);
    gyy = fmaf(dy,dy,gyy); gyz = fmaf(dy,dz,gyz); gzz = fmaf(dz,dz,gzz);
  }
  *(float2*)&xd[0*R_TOT + rbase + sub*2] = make_float2(ox[0],ox[1]);
  *(float2*)&xd[1*R_TOT + rbase + sub*2] = make_float2(oy[0],oy[1]);
  *(float2*)&xd[2*R_TOT + rbase + sub*2] = make_float2(oz[0],oz[1]);

  float S[27];
  S[0]=sdx; S[1]=sdy; S[2]=sdz; S[3]=2.f*ax; S[4]=2.f*ay; S[5]=2.f*az;
  S[6]=gxx; S[7]=gxy; S[8]=gxz; S[9]=sdx*ax; S[10]=sdx*ay; S[11]=sdx*az;
  S[12]=gyy; S[13]=gyz; S[14]=sdy*ax; S[15]=sdy*ay; S[16]=sdy*az;
  S[17]=gzz; S[18]=sdz*ax; S[19]=sdz*ay; S[20]=sdz*az;
  S[21]=2.f*ax*ax; S[22]=2.f*ax*ay; S[23]=2.f*ax*az;
  S[24]=2.f*ay*ay; S[25]=2.f*ay*az; S[26]=2.f*az*az;
  #pragma unroll
  for (int i = 0; i < 27; ++i){
    float v = S[i];
    v += __shfl_down(v,32); v += __shfl_down(v,16); v += __shfl_down(v,8);
    v += __shfl_down(v,4);  v += __shfl_down(v,2);  v += __shfl_down(v,1);
    if ((tid & 63) == 0) wstats[tid>>6][i] = v;
  }
  __syncthreads();
  if (tid < 27)
    part1[blockIdx.x*28 + tid] = (wstats[0][tid]+wstats[1][tid]) + (wstats[2][tid]+wstats[3][tid]);
}

// ---------------- Kernel B0: reduce part1 over 2048 blocks ------------------------
__global__ __launch_bounds__(256) void kB0(const float* __restrict__ part1,
                                           float* __restrict__ st)   // [27]
{
  __shared__ float red[256];
  const int i = blockIdx.x;  // 0..26
  float ssum = 0.f;
  for (int k = threadIdx.x; k < 2048; k += 256) ssum += part1[k*28 + i];
  red[threadIdx.x] = ssum;
  __syncthreads();
  for (int w = 128; w > 0; w >>= 1){
    if (threadIdx.x < w) red[threadIdx.x] += red[threadIdx.x + w];
    __syncthreads();
  }
  if (threadIdx.x == 0) st[i] = red[0];
}

// ---------------- Kernel B2: finalize BN1 scale/bias (analytic) -------------------
__global__ __launch_bounds__(64) void kB2(const float* __restrict__ st_in,
                                          const float* __restrict__ W1,
                                          const float* __restrict__ g1,
                                          const float* __restrict__ b1,
                                          float* __restrict__ sb1)
{
  __shared__ float st[27];
  const int tid = threadIdx.x;
  if (tid < 27) st[tid] = st_in[tid];
  __syncthreads();
  const int o = tid;
  const float invR = 1.f / (float)R_TOT;
  float mu[6], w[6];
  #pragma unroll
  for (int c = 0; c < 6; ++c){ mu[c] = st[c]*invR; w[c] = W1[o*6+c]; }
  float mean = 0.f;
  #pragma unroll
  for (int c = 0; c < 6; ++c) mean = fmaf(w[c], mu[c], mean);
  float var = 0.f;
  #pragma unroll
  for (int c = 0; c < 6; ++c)
    #pragma unroll
    for (int c2 = 0; c2 < 6; ++c2){
      const int lo = c < c2 ? c : c2, hi = c < c2 ? c2 : c;
      const int ti = 6*lo - lo*(lo-1)/2 + (hi - lo);
      float cov = st[6+ti]*invR - mu[c]*mu[c2];
      var = fmaf(w[c]*w[c2], cov, var);
    }
  float sc = g1[o] / sqrtf(var + 1e-5f);
  sb1[o] = sc; sb1[64+o] = b1[o] - mean*sc;
}

// ---------------- shared producer: 16 channels x 4 rows of h1n --------------------
template<int MODE> // 0: rows rg*4+j (kC), 1: rows rg+64*j (kE)
__device__ __forceinline__ void produce16(const float* __restrict__ xd,
                                          const float* __restrict__ a,
                                          int chbase, int rg, int cg,
                                          const float* sW1, const float* ss1,
                                          const float* st1, float (&h)[4][16])
{
  float xv[6][4];
  if (MODE == 0){
    #pragma unroll
    for (int c = 0; c < 3; ++c){
      const float4 t = *(const float4*)&xd[c*R_TOT + chbase + rg*4];
      xv[c][0]=t.x; xv[c][1]=t.y; xv[c][2]=t.z; xv[c][3]=t.w;
    }
    const int qg = (chbase + rg*4) >> 5;
    const int bb = qg >> 11, n = qg & 2047;
    #pragma unroll
    for (int c = 0; c < 3; ++c){
      const float qv = a[(bb*3+c)*NPT + n];
      xv[3+c][0]=qv; xv[3+c][1]=qv; xv[3+c][2]=qv; xv[3+c][3]=qv;
    }
  } else {
    #pragma unroll
    for (int j = 0; j < 4; ++j){
      const int r = chbase + rg + 64*j;
      #pragma unroll
      for (int c = 0; c < 3; ++c) xv[c][j] = xd[c*R_TOT + r];
      const int qg = r >> 5;
      const int bb = qg >> 11, n = qg & 2047;
      #pragma unroll
      for (int c = 0; c < 3; ++c) xv[3+c][j] = a[(bb*3+c)*NPT + n];
    }
  }
  #pragma unroll
  for (int i = 0; i < 16; ++i){
    const int o = cg*16 + i;
    const float w0=sW1[o*6+0], w1=sW1[o*6+1], w2=sW1[o*6+2];
    const float w3=sW1[o*6+3], w4=sW1[o*6+4], w5=sW1[o*6+5];
    const float s = ss1[o], t = st1[o];
    #pragma unroll
    for (int j = 0; j < 4; ++j){
      float acc = xv[0][j]*w0;
      acc = fmaf(xv[1][j], w1, acc); acc = fmaf(xv[2][j], w2, acc);
      acc = fmaf(xv[3][j], w3, acc); acc = fmaf(xv[4][j], w4, acc);
      acc = fmaf(xv[5][j], w5, acc);
      float y = fmaf(acc, s, t);
      h[j][i] = y > 0.f ? y : 0.2f*y;
    }
  }
}

// ---------------- Kernel C: Gram of h1n (MFMA) + mean(h1n) partials ---------------
__global__ __launch_bounds__(256) void kC(const float* __restrict__ xd,
                                          const float* __restrict__ a,
                                          const float* __restrict__ W1,
                                          const float* __restrict__ sb1,
                                          float* __restrict__ Gpart)   // [512][4160]
{
  __shared__ unsigned short hT[64*264];   // [chan][row] bf16, pad 8
  __shared__ float sW1[384], ss1[64], st1[64];
  __shared__ float G[4096];
  const int tid = threadIdx.x, rg = tid & 63, cg = tid >> 6;
  const int l15 = rg & 15, lg = rg >> 4;
  for (int i = tid; i < 384; i += 256) sW1[i] = W1[i];
  if (tid < 64){ ss1[tid] = sb1[tid]; st1[tid] = sb1[64+tid]; }
  __syncthreads();

  f32x4 acc[10];
  #pragma unroll
  for (int i = 0; i < 10; ++i) acc[i] = (f32x4){0.f,0.f,0.f,0.f};
  float mu[16];
  #pragma unroll
  for (int i = 0; i < 16; ++i) mu[i] = 0.f;

  for (int ch = blockIdx.x; ch < NCHUNK; ch += gridDim.x){
    float h[4][16];
    produce16<0>(xd, a, ch*256, rg, cg, sW1, ss1, st1, h);
    #pragma unroll
    for (int i = 0; i < 16; ++i){
      mu[i] += (h[0][i] + h[1][i]) + (h[2][i] + h[3][i]);
      *(int2*)&hT[(cg*16+i)*264 + rg*4] =
          make_int2(pk2(h[0][i],h[1][i]), pk2(h[2][i],h[3][i]));
    }
    __syncthreads();
    #pragma unroll
    for (int s = 0; s < 2; ++s){
      const int kb = cg*64 + s*32 + (lg << 3);
      bf16x8 f0 = *(bf16x8*)&hT[( 0 + l15)*264 + kb];
      bf16x8 f1 = *(bf16x8*)&hT[(16 + l15)*264 + kb];
      bf16x8 f2 = *(bf16x8*)&hT[(32 + l15)*264 + kb];
      bf16x8 f3 = *(bf16x8*)&hT[(48 + l15)*264 + kb];
      acc[0]=MFMA(f0,f0,acc[0]); acc[1]=MFMA(f0,f1,acc[1]);
      acc[2]=MFMA(f0,f2,acc[2]); acc[3]=MFMA(f0,f3,acc[3]);
      acc[4]=MFMA(f1,f1,acc[4]); acc[5]=MFMA(f1,f2,acc[5]);
      acc[6]=MFMA(f1,f3,acc[6]); acc[7]=MFMA(f2,f2,acc[7]);
      acc[8]=MFMA(f2,f3,acc[8]); acc[9]=MFMA(f3,f3,acc[9]);
    }
    __syncthreads();
  }

  for (int i = tid; i < 4096; i += 256) G[i] = 0.f;
  __syncthreads();
  const int TI[10] = {0,0,0,0,1,1,1,2,2,3};
  const int TJ[10] = {0,1,2,3,1,2,3,2,3,3};
  for (int w = 0; w < 4; ++w){
    if (cg == w){
      #pragma unroll
      for (int t = 0; t < 10; ++t){
        const int ti = TI[t], tj = TJ[t];
        #pragma unroll
        for (int j = 0; j < 4; ++j){
          const int gi = ti*16 + lg*4 + j, gj = tj*16 + l15;
          const float v = acc[t][j];
          G[gi*64 + gj] += v;
          if (ti != tj) G[gj*64 + gi] += v;
        }
      }
    }
    __syncthreads();
  }
  #pragma unroll
  for (int i = 0; i < 16; ++i){
    float v = mu[i];
    v += __shfl_down(v,32); v += __shfl_down(v,16); v += __shfl_down(v,8);
    v += __shfl_down(v,4);  v += __shfl_down(v,2);  v += __shfl_down(v,1);
    if (rg == 0) Gpart[blockIdx.x*4160 + 4096 + cg*16 + i] = v;
  }
  for (int i = tid; i < 4096; i += 256) Gpart[blockIdx.x*4160 + i] = G[i];
}

// ---------------- Kernel D1: reduce Gram/mean partials (parallel, 260 blocks) -----
__global__ __launch_bounds__(256) void kD1(const float* __restrict__ Gpart,
                                           float* __restrict__ Gsum)
{
  __shared__ float red[16][17];
  const int tid = threadIdx.x;
  const int el = tid & 15, g = tid >> 4;     // 16 e-values x 16 bk-groups
  const int e = blockIdx.x*16 + el;
  float s = 0.f;
  if (e < 4160){
    const int b0 = g*32;
    for (int bk = b0; bk < b0 + 32; ++bk) s += Gpart[bk*4160 + e];
  }
  red[el][g] = s;
  __syncthreads();
  if (g == 0 && e < 4160){
    float t = 0.f;
    #pragma unroll
    for (int k = 0; k < 16; ++k) t += red[el][k];
    Gsum[e] = t;
  }
}

// ---------------- Kernel D2: finalize BN2 scale/bias (analytic) -------------------
__global__ __launch_bounds__(64) void kD2(const float* __restrict__ Gsum,
                                          const float* __restrict__ W2,
                                          const float* __restrict__ g2,
                                          const float* __restrict__ b2p,
                                          float* __restrict__ sb2)
{
  const int o = blockIdx.x, j = threadIdx.x;
  const float invR = 1.f / (float)R_TOT;
  const float muj = Gsum[4096 + j]*invR;
  float t = 0.f;
  for (int k = 0; k < 64; ++k){
    float cov = fmaf(-(Gsum[4096 + k]*invR), muj, Gsum[k*64 + j]*invR);
    t = fmaf(W2[o*64 + k], cov, t);
  }
  const float wj = W2[o*64 + j];
  float vpart = wj*t, mpart = wj*muj;
  vpart += __shfl_down(vpart,32); mpart += __shfl_down(mpart,32);
  vpart += __shfl_down(vpart,16); mpart += __shfl_down(mpart,16);
  vpart += __shfl_down(vpart, 8); mpart += __shfl_down(mpart, 8);
  vpart += __shfl_down(vpart, 4); mpart += __shfl_down(mpart, 4);
  vpart += __shfl_down(vpart, 2); mpart += __shfl_down(mpart, 2);
  vpart += __shfl_down(vpart, 1); mpart += __shfl_down(mpart, 1);
  if (j == 0){
    float sc = g2[o] / sqrtf(vpart + 1e-5f);
    sb2[o] = sc; sb2[64+o] = b2p[o] - mpart*sc;
  }
}

// ---------------- Kernel E: layer2 MFMA + BN2 + LReLU + max over K + output -------
__global__ __launch_bounds__(256) void kE(const float* __restrict__ xd,
                                          const float* __restrict__ a,
                                          const float* __restrict__ W1,
                                          const float* __restrict__ sb1,
                                          const float* __restrict__ W2,
                                          const float* __restrict__ sb2,
                                          float* __restrict__ out)
{
  __shared__ unsigned short hN[256*72];   // [row][chan] bf16, pad 8
  __shared__ float sW1[384], ss1[64], st1[64];
  __shared__ float outq[64*8];
  const int tid = threadIdx.x, rg = tid & 63, cg = tid >> 6;
  const int l15 = rg & 15, lg = rg >> 4;
  for (int i = tid; i < 384; i += 256) sW1[i] = W1[i];
  if (tid < 64){ ss1[tid] = sb1[tid]; st1[tid] = sb1[64+tid]; }

  float s2v[4], t2v[4];
  #pragma unroll
  for (int ct = 0; ct < 4; ++ct){ s2v[ct] = sb2[ct*16 + l15]; t2v[ct] = sb2[64 + ct*16 + l15]; }
  bf16x8 bfr[4][2];
  #pragma unroll
  for (int ct = 0; ct < 4; ++ct)
    #pragma unroll
    for (int kk = 0; kk < 2; ++kk){
      const int o = ct*16 + l15, kb = kk*32 + (lg << 3);
      const float4 wa = *(const float4*)&W2[o*64 + kb];
      const float4 wb = *(const float4*)&W2[o*64 + kb + 4];
      int4 t4 = make_int4(pk2(wa.x,wa.y), pk2(wa.z,wa.w), pk2(wb.x,wb.y), pk2(wb.z,wb.w));
      bfr[ct][kk] = __builtin_bit_cast(bf16x8, t4);
    }
  __syncthreads();

  for (int ch = blockIdx.x; ch < NCHUNK; ch += gridDim.x){
    const int bb = ch >> 8, n0 = (ch & 255)*8;
    float h[4][16];
    produce16<1>(xd, a, ch*256, rg, cg, sW1, ss1, st1, h);
    #pragma unroll
    for (int j = 0; j < 4; ++j){
      const int base = (rg + 64*j)*72 + cg*16;
      *(int4*)&hN[base] = make_int4(pk2(h[j][0],h[j][1]), pk2(h[j][2],h[j][3]),
                                    pk2(h[j][4],h[j][5]), pk2(h[j][6],h[j][7]));
      *(int4*)&hN[base+8] = make_int4(pk2(h[j][8],h[j][9]),  pk2(h[j][10],h[j][11]),
                                      pk2(h[j][12],h[j][13]), pk2(h[j][14],h[j][15]));
    }
    __syncthreads();

    f32x4 acc[4][4];
    #pragma unroll
    for (int rt = 0; rt < 4; ++rt)
      #pragma unroll
      for (int ct = 0; ct < 4; ++ct) acc[rt][ct] = (f32x4){0.f,0.f,0.f,0.f};
    #pragma unroll
    for (int kk = 0; kk < 2; ++kk){
      bf16x8 af[4];
      #pragma unroll
      for (int rt = 0; rt < 4; ++rt){
        const int row = cg*64 + rt*16 + l15;
        af[rt] = *(bf16x8*)&hN[row*72 + kk*32 + (lg << 3)];
      }
      #pragma unroll
      for (int rt = 0; rt < 4; ++rt)
        #pragma unroll
        for (int ct = 0; ct < 4; ++ct)
          acc[rt][ct] = MFMA(af[rt], bfr[ct][kk], acc[rt][ct]);
    }

    float qm[2][4];
    #pragma unroll
    for (int q = 0; q < 2; ++q)
      #pragma unroll
      for (int ct = 0; ct < 4; ++ct) qm[q][ct] = -1e30f;
    #pragma unroll
    for (int rt = 0; rt < 4; ++rt)
      #pragma unroll
      for (int ct = 0; ct < 4; ++ct){
        float m1 = -1e30f;
        #pragma unroll
        for (int j = 0; j < 4; ++j){
          float y = fmaf(acc[rt][ct][j], s2v[ct], t2v[ct]);
          y = y > 0.f ? y : 0.2f*y;
          m1 = fmaxf(m1, y);
        }
        m1 = fmaxf(m1, __shfl_xor(m1, 16));
        m1 = fmaxf(m1, __shfl_xor(m1, 32));
        qm[rt>>1][ct] = fmaxf(qm[rt>>1][ct], m1);
      }
    if (lg == 0){
      #pragma unroll
      for (int q = 0; q < 2; ++q)
        #pragma unroll
        for (int ct = 0; ct < 4; ++ct)
          outq[(ct*16 + l15)*8 + cg*2 + q] = qm[q][ct];
    }
    __syncthreads();
    {
      const int o = tid >> 2, qi = tid & 3;
      float2 v; v.x = outq[o*8 + qi*2]; v.y = outq[o*8 + qi*2 + 1];
      *(float2*)&out[(bb*64 + o)*NPT + n0 + qi*2] = v;
    }
    __syncthreads();
  }
}

// ---------------- launch ----------------------------------------------------------
extern "C" void kernel_launch(void* const* d_in, const int* in_sizes, int n_in,
                              void* d_out, int out_size, void* d_ws, size_t ws_size,
                              hipStream_t stream)
{
  const float* a  = (const float*)d_in[0];
  const float* b  = (const float*)d_in[1];
  const float* W1 = (const float*)d_in[2];
  const float* g1 = (const float*)d_in[3];
  const float* b1 = (const float*)d_in[4];
  const float* W2 = (const float*)d_in[5];
  const float* g2 = (const float*)d_in[6];
  const float* b2 = (const float*)d_in[7];
  float* out = (float*)d_out;
  char* ws = (char*)d_ws;
  if (ws_size < 21177600u) return;  // insufficient scratch -> distinct failure signature

  float* xd    = (float*)(ws);                 // 3*R_TOT f32 = 12,582,912 B
  float* sb1   = (float*)(ws + 12640256);      // 128 f32
  float* Gsum  = (float*)(ws + 12640768);      // 4160 f32
  float* sb2   = (float*)(ws + 12657408);      // 128 f32
  float* Gpart = (float*)(ws + 12657920);      // 512*4160 f32 = 8,519,680 B
  float* part1 = Gpart;                        // [2048][28] aliased into Gpart
  float* stsum = Gpart + 2048*28;              // [27] aliased after part1
                                               // (both consumed before kC writes Gpart)

  kA <<<2048, 256, 0, stream>>>(a, b, xd, part1);
  kB0<<<27,  256, 0, stream>>>(part1, stsum);
  kB2<<<1,    64, 0, stream>>>(stsum, W1, g1, b1, sb1);
  kC <<<512, 256, 0, stream>>>(xd, a, W1, sb1, Gpart);
  kD1<<<260, 256, 0, stream>>>(Gpart, Gsum);
  kD2<<<64,  64, 0, stream>>>(Gsum, W2, g2, b2, sb2);
  kE <<<1024, 256, 0, stream>>>(xd, a, W1, sb1, W2, sb2, out);
}